// Round 2
// baseline (294.998 us; speedup 1.0000x reference)
//
#include <hip/hip_runtime.h>

typedef __attribute__((ext_vector_type(8))) short short8;
typedef __attribute__((ext_vector_type(4))) float float4v;
typedef __attribute__((ext_vector_type(4))) short short4v;

#define B_ 2
#define S_ 2048
#define D_ 1024
#define H_ 16
#define HD_ 64
#define M_ 4096
#define LOG2E 1.442695040888963f

__device__ __forceinline__ unsigned short f2bf(float f) {
  unsigned int u = __builtin_bit_cast(unsigned int, f);
  u += 0x7fffu + ((u >> 16) & 1u);   // RNE (finite values only)
  return (unsigned short)(u >> 16);
}

__device__ __forceinline__ void gload_lds16(const void* g, void* l) {
  __builtin_amdgcn_global_load_lds(
      (const __attribute__((address_space(1))) void*)g,
      (__attribute__((address_space(3))) void*)l, 16, 0, 0);
}

// ---------------------------------------------------------------------------
// f32 -> bf16 cast: x (4 segs of 1M) + qw/kw/vw/ow (1M each) into d_ws.
// ---------------------------------------------------------------------------
__global__ __launch_bounds__(256, 4) void cvt_kernel(
    const float* __restrict__ x,  const float* __restrict__ qw,
    const float* __restrict__ kw, const float* __restrict__ vw,
    const float* __restrict__ ow, unsigned short* __restrict__ dst)
{
  const int seg = blockIdx.y;
  const float* src;
  size_t doff;
  if (seg < 4)       { src = x + (size_t)seg * 1048576; doff = (size_t)seg * 1048576; }
  else if (seg == 4) { src = qw; doff = 4194304u; }
  else if (seg == 5) { src = kw; doff = 4194304u + 1048576u; }
  else if (seg == 6) { src = vw; doff = 4194304u + 2097152u; }
  else               { src = ow; doff = 4194304u + 3145728u; }
  const size_t i = ((size_t)blockIdx.x * 256 + threadIdx.x) * 4;
  float4v v = *(const float4v*)(src + i);
  short4v p;
#pragma unroll
  for (int r = 0; r < 4; ++r) p[r] = (short)f2bf(v[r]);
  *(short4v*)(dst + doff + i) = p;
}

// ---------------------------------------------------------------------------
// GEMM: out = X @ W^T + bias.  X:[4096,1024] bf16, W:[1024,1024] bf16
// (rows = output cols), bias f32.  128x128 tile, BK=32, 4 waves.
// mode 0: plain f32 [4096,1024] out; mode 1: bf16 head-split [B,H,S,hd];
// mode 2: bf16 transposed per-head [B,H,hd,S] (for V).
// blockIdx.z selects among three weight sets (fused QKV launch).
// ---------------------------------------------------------------------------
__global__ __launch_bounds__(256, 2) void gemm_kernel(
    const unsigned short* __restrict__ X,
    const unsigned short* __restrict__ W0, const unsigned short* __restrict__ W1,
    const unsigned short* __restrict__ W2,
    const float* __restrict__ Bi0, const float* __restrict__ Bi1,
    const float* __restrict__ Bi2,
    unsigned short* O0, unsigned short* O1, unsigned short* O2,
    float* OutF, int md0, int md1, int md2)
{
  const int z = blockIdx.z;
  const unsigned short* W  = (z == 0) ? W0  : ((z == 1) ? W1  : W2);
  const float* Bi          = (z == 0) ? Bi0 : ((z == 1) ? Bi1 : Bi2);
  unsigned short* Out      = (z == 0) ? O0  : ((z == 1) ? O1  : O2);
  const int mode           = (z == 0) ? md0 : ((z == 1) ? md1 : md2);

  __shared__ char smem[128 * 32 * 2 * 2];  // A tile 8KB + B tile 8KB
  char* As = smem;
  char* Bs = smem + 128 * 32 * 2;

  const int t = threadIdx.x, l = t & 63;
  const int w = t >> 6, lr = l & 15, lg = l >> 4;
  const int n0 = blockIdx.x * 128, m0 = blockIdx.y * 128;
  const int wm = (w >> 1) * 64, wn = (w & 1) * 64;

  float4v acc[4][4];
#pragma unroll
  for (int i = 0; i < 4; ++i)
#pragma unroll
    for (int j = 0; j < 4; ++j) acc[i][j] = (float4v){0.f, 0.f, 0.f, 0.f};

  const int c0 = t, c1 = t + 256;
  const int r0 = c0 >> 2, k80 = (c0 & 3) * 8;
  const int r1 = c1 >> 2, k81 = (c1 & 3) * 8;

  for (int k0 = 0; k0 < 1024; k0 += 32) {
    __syncthreads();
    gload_lds16(X + (size_t)(m0 + r0) * 1024 + k0 + k80, As + c0 * 16);
    gload_lds16(X + (size_t)(m0 + r1) * 1024 + k0 + k81, As + c1 * 16);
    gload_lds16(W + (size_t)(n0 + r0) * 1024 + k0 + k80, Bs + c0 * 16);
    gload_lds16(W + (size_t)(n0 + r1) * 1024 + k0 + k81, Bs + c1 * 16);
    __syncthreads();

    short8 af[4], bfr[4];
#pragma unroll
    for (int i = 0; i < 4; ++i)
      af[i] = *(const short8*)(As + (wm + i * 16 + lr) * 64 + lg * 16);
#pragma unroll
    for (int j = 0; j < 4; ++j)
      bfr[j] = *(const short8*)(Bs + (wn + j * 16 + lr) * 64 + lg * 16);
#pragma unroll
    for (int i = 0; i < 4; ++i)
#pragma unroll
      for (int j = 0; j < 4; ++j)
        acc[i][j] = __builtin_amdgcn_mfma_f32_16x16x32_bf16(af[i], bfr[j], acc[i][j], 0, 0, 0);
  }

  // epilogue: bias + layout transform + store
  float bv[4];
#pragma unroll
  for (int j = 0; j < 4; ++j) bv[j] = Bi[n0 + wn + j * 16 + lr];

#pragma unroll
  for (int i = 0; i < 4; ++i) {
    const int rowb = m0 + wm + i * 16 + lg * 4;
#pragma unroll
    for (int j = 0; j < 4; ++j) {
      const int col = n0 + wn + j * 16 + lr;
      if (mode == 2) {
        const int b = rowb >> 11, s = rowb & 2047;
        const int hh = col >> 6, d = col & 63;
        short4v pk;
#pragma unroll
        for (int r = 0; r < 4; ++r) pk[r] = (short)f2bf(acc[i][j][r] + bv[j]);
        *(short4v*)(Out + ((size_t)(b * H_ + hh) * HD_ + d) * S_ + s) = pk;
      } else if (mode == 1) {
#pragma unroll
        for (int r = 0; r < 4; ++r) {
          const int row = rowb + r;
          const int b = row >> 11, s = row & 2047;
          const int hh = col >> 6, d = col & 63;
          Out[((size_t)(b * H_ + hh) * S_ + s) * HD_ + d] = f2bf(acc[i][j][r] + bv[j]);
        }
      } else {
#pragma unroll
        for (int r = 0; r < 4; ++r)
          OutF[(size_t)(rowb + r) * 1024 + col] = acc[i][j][r] + bv[j];
      }
    }
  }
}

// ---------------------------------------------------------------------------
// Flash attention with ALiBi + causal mask.
// Q,K: [B,H,S,hd] bf16;  VT: [B,H,hd,S] bf16;  O: [B*S, H*hd] bf16.
// BLOCK_M = 128 (4 waves x 32 rows), BLOCK_N = 64.  Base-2 online softmax.
// Per-row ALiBi term -slope*q_pos is softmax-invariant and dropped.
// LDS rows padded to 144 B to avoid bank conflicts.
// ---------------------------------------------------------------------------
__global__ __launch_bounds__(256, 2) void attn_kernel(
    const unsigned short* __restrict__ Q, const unsigned short* __restrict__ K,
    const unsigned short* __restrict__ VT, unsigned short* __restrict__ O)
{
  __shared__ char smem[9216 * 2 + 18432];  // K(64x72) + V(64x72) + P(128x72) bf16
  char* Ks = smem;
  char* Vs = smem + 9216;
  char* Ps = smem + 18432;

  const int t = threadIdx.x, l = t & 63;
  const int w = t >> 6, lr = l & 15, lg = l >> 4;
  const int ib = blockIdx.x, bh = blockIdx.y;
  const int h = bh & 15;

  const unsigned short* qbp = Q + (size_t)bh * S_ * HD_;
  const unsigned short* kbp = K + (size_t)bh * S_ * HD_;
  const unsigned short* vbp = VT + (size_t)bh * HD_ * S_;

  short8 qf[2][2];
#pragma unroll
  for (int mi = 0; mi < 2; ++mi)
#pragma unroll
    for (int ks = 0; ks < 2; ++ks)
      qf[mi][ks] = *(const short8*)(qbp + (size_t)(ib * 128 + w * 32 + mi * 16 + lr) * HD_ + ks * 32 + lg * 8);

  float4v o_acc[2][4];
#pragma unroll
  for (int mi = 0; mi < 2; ++mi)
#pragma unroll
    for (int dt = 0; dt < 4; ++dt) o_acc[mi][dt] = (float4v){0.f, 0.f, 0.f, 0.f};

  float m_st[2][4], l_st[2][4];
#pragma unroll
  for (int mi = 0; mi < 2; ++mi)
#pragma unroll
    for (int r = 0; r < 4; ++r) { m_st[mi][r] = -1e30f; l_st[mi][r] = 0.f; }

  const float slope2 = exp2f(-0.5f * (float)(h + 1)) * LOG2E;  // base-2 ALiBi slope
  const float qksc = 0.125f * LOG2E;                            // 1/sqrt(64) * log2(e)

  char* pw = Ps + w * (32 * 144);  // wave-private P region
  const int jmax = 2 * ib + 1;

  for (int j = 0; j <= jmax; ++j) {
    __syncthreads();
#pragma unroll
    for (int cc = 0; cc < 2; ++cc) {
      const int c = t + cc * 256;
      const int row = c >> 3, co = (c & 7) * 8;
      float4v kd = *(const float4v*)(kbp + (size_t)(j * 64 + row) * HD_ + co);
      float4v vd = *(const float4v*)(vbp + (size_t)row * S_ + j * 64 + co);
      *(float4v*)(Ks + row * 144 + co * 2) = kd;
      *(float4v*)(Vs + row * 144 + co * 2) = vd;
    }
    __syncthreads();

    // S = Q K^T  (scaled into base-2 domain)
    short8 kf[4][2];
#pragma unroll
    for (int nj = 0; nj < 4; ++nj)
#pragma unroll
      for (int ks = 0; ks < 2; ++ks)
        kf[nj][ks] = *(const short8*)(Ks + (nj * 16 + lr) * 144 + ks * 64 + lg * 16);

    float4v s_acc[2][4];
#pragma unroll
    for (int mi = 0; mi < 2; ++mi)
#pragma unroll
      for (int nj = 0; nj < 4; ++nj) {
        s_acc[mi][nj] = (float4v){0.f, 0.f, 0.f, 0.f};
#pragma unroll
        for (int ks = 0; ks < 2; ++ks)
          s_acc[mi][nj] = __builtin_amdgcn_mfma_f32_16x16x32_bf16(qf[mi][ks], kf[nj][ks], s_acc[mi][nj], 0, 0, 0);
      }

    float cb[4];
#pragma unroll
    for (int nj = 0; nj < 4; ++nj) cb[nj] = slope2 * (float)(j * 64 + nj * 16 + lr);

    const bool domask = (j >= 2 * ib);
#pragma unroll
    for (int mi = 0; mi < 2; ++mi)
#pragma unroll
      for (int nj = 0; nj < 4; ++nj)
#pragma unroll
        for (int r = 0; r < 4; ++r) {
          float sv = s_acc[mi][nj][r] * qksc + cb[nj];
          if (domask) {
            const int qpos = ib * 128 + w * 32 + mi * 16 + lg * 4 + r;
            const int kpos = j * 64 + nj * 16 + lr;
            if (kpos > qpos) sv = -1e30f;
          }
          s_acc[mi][nj][r] = sv;
        }

    // online softmax per row-slot; 16 lanes sharing lg hold one row
#pragma unroll
    for (int mi = 0; mi < 2; ++mi)
#pragma unroll
      for (int r = 0; r < 4; ++r) {
        float mx = fmaxf(fmaxf(s_acc[mi][0][r], s_acc[mi][1][r]),
                         fmaxf(s_acc[mi][2][r], s_acc[mi][3][r]));
#pragma unroll
        for (int d = 1; d < 16; d <<= 1) mx = fmaxf(mx, __shfl_xor(mx, d, 64));
        const float mn = fmaxf(m_st[mi][r], mx);
        const float a = exp2f(m_st[mi][r] - mn);
        m_st[mi][r] = mn;
        float rs = 0.f;
#pragma unroll
        for (int nj = 0; nj < 4; ++nj) {
          const float p = exp2f(s_acc[mi][nj][r] - mn);
          s_acc[mi][nj][r] = p;
          rs += p;
        }
#pragma unroll
        for (int d = 1; d < 16; d <<= 1) rs += __shfl_xor(rs, d, 64);
        l_st[mi][r] = a * l_st[mi][r] + rs;
#pragma unroll
        for (int dt = 0; dt < 4; ++dt) o_acc[mi][dt][r] *= a;
      }

    // P (C-layout) -> LDS row-major [q][key], bf16, wave-private
#pragma unroll
    for (int mi = 0; mi < 2; ++mi)
#pragma unroll
      for (int nj = 0; nj < 4; ++nj)
#pragma unroll
        for (int r = 0; r < 4; ++r)
          *(unsigned short*)(pw + (mi * 16 + lg * 4 + r) * 144 + (nj * 16 + lr) * 2) =
              f2bf(s_acc[mi][nj][r]);

    __syncthreads();

    // O += P V
    short8 vf[4][2];
#pragma unroll
    for (int dt = 0; dt < 4; ++dt)
#pragma unroll
      for (int ks = 0; ks < 2; ++ks)
        vf[dt][ks] = *(const short8*)(Vs + (dt * 16 + lr) * 144 + ks * 64 + lg * 16);
    short8 pf[2][2];
#pragma unroll
    for (int mi = 0; mi < 2; ++mi)
#pragma unroll
      for (int ks = 0; ks < 2; ++ks)
        pf[mi][ks] = *(const short8*)(pw + (mi * 16 + lr) * 144 + ks * 64 + lg * 16);
#pragma unroll
    for (int mi = 0; mi < 2; ++mi)
#pragma unroll
      for (int dt = 0; dt < 4; ++dt)
#pragma unroll
        for (int ks = 0; ks < 2; ++ks)
          o_acc[mi][dt] = __builtin_amdgcn_mfma_f32_16x16x32_bf16(pf[mi][ks], vf[dt][ks], o_acc[mi][dt], 0, 0, 0);
  }

  // finalize: O /= l, write to [B*S, H*hd] bf16
  const int brow = (bh >> 4) * S_;
#pragma unroll
  for (int mi = 0; mi < 2; ++mi)
#pragma unroll
    for (int r = 0; r < 4; ++r) {
      const float inv = 1.0f / l_st[mi][r];
      const int qpos = ib * 128 + w * 32 + mi * 16 + lg * 4 + r;
#pragma unroll
      for (int dt = 0; dt < 4; ++dt) {
        const int col = h * HD_ + dt * 16 + lr;
        O[(size_t)(brow + qpos) * 1024 + col] = f2bf(o_acc[mi][dt][r] * inv);
      }
    }
}

extern "C" void kernel_launch(void* const* d_in, const int* in_sizes, int n_in,
                              void* d_out, int out_size, void* d_ws, size_t ws_size,
                              hipStream_t stream) {
  (void)in_sizes; (void)n_in; (void)out_size; (void)ws_size;
  const float* x  = (const float*)d_in[0];
  const float* qw = (const float*)d_in[1];
  const float* qb = (const float*)d_in[2];
  const float* kw = (const float*)d_in[3];
  const float* kb = (const float*)d_in[4];
  const float* vw = (const float*)d_in[5];
  const float* vb = (const float*)d_in[6];
  const float* ow = (const float*)d_in[7];
  const float* ob = (const float*)d_in[8];
  float* out = (float*)d_out;

  unsigned short* xb  = (unsigned short*)d_ws;              // [4096,1024] bf16
  unsigned short* qwb = xb  + (size_t)M_ * D_;              // [1024,1024] bf16
  unsigned short* kwb = qwb + (size_t)D_ * D_;
  unsigned short* vwb = kwb + (size_t)D_ * D_;
  unsigned short* owb = vwb + (size_t)D_ * D_;
  unsigned short* qws = owb + (size_t)D_ * D_;              // [B,H,S,hd]
  unsigned short* kws = qws + (size_t)M_ * D_;              // [B,H,S,hd]
  unsigned short* vws = kws + (size_t)M_ * D_;              // [B,H,hd,S]
  unsigned short* aws = vws + (size_t)M_ * D_;              // [B*S, H*hd]

  // f32 -> bf16 casts
  cvt_kernel<<<dim3(1024, 8), dim3(256), 0, stream>>>(x, qw, kw, vw, ow, xb);
  // fused QKV projections (z: 0=Q, 1=K, 2=V-transposed)
  gemm_kernel<<<dim3(8, 32, 3), dim3(256), 0, stream>>>(
      xb, qwb, kwb, vwb, qb, kb, vb, qws, kws, vws, out, 1, 1, 2);
  // flash attention
  attn_kernel<<<dim3(16, 32), dim3(256), 0, stream>>>(qws, kws, vws, aws);
  // output projection (f32 out)
  gemm_kernel<<<dim3(8, 32, 1), dim3(256), 0, stream>>>(
      aws, owb, owb, owb, ob, ob, ob, aws, aws, aws, out, 0, 0, 0);
}

// Round 3
// 205.592 us; speedup vs baseline: 1.4349x; 1.4349x over previous
//
#include <hip/hip_runtime.h>

typedef __attribute__((ext_vector_type(8))) short short8;
typedef __attribute__((ext_vector_type(4))) float float4v;
typedef __attribute__((ext_vector_type(4))) short short4v;

#define B_ 2
#define S_ 2048
#define D_ 1024
#define H_ 16
#define HD_ 64
#define M_ 4096
#define LOG2E 1.442695040888963f

__device__ __forceinline__ unsigned short f2bf(float f) {
  unsigned int u = __builtin_bit_cast(unsigned int, f);
  u += 0x7fffu + ((u >> 16) & 1u);   // RNE (finite values only)
  return (unsigned short)(u >> 16);
}

__device__ __forceinline__ void gload_lds16(const void* g, void* l) {
  __builtin_amdgcn_global_load_lds(
      (const __attribute__((address_space(1))) void*)g,
      (__attribute__((address_space(3))) void*)l, 16, 0, 0);
}

// ---------------------------------------------------------------------------
// f32 -> bf16 cast: x (4 segs of 1M) + qw/kw/vw/ow (1M each) into d_ws.
// ---------------------------------------------------------------------------
__global__ __launch_bounds__(256, 4) void cvt_kernel(
    const float* __restrict__ x,  const float* __restrict__ qw,
    const float* __restrict__ kw, const float* __restrict__ vw,
    const float* __restrict__ ow, unsigned short* __restrict__ dst)
{
  const int seg = blockIdx.y;
  const float* src;
  size_t doff;
  if (seg < 4)       { src = x + (size_t)seg * 1048576; doff = (size_t)seg * 1048576; }
  else if (seg == 4) { src = qw; doff = 4194304u; }
  else if (seg == 5) { src = kw; doff = 4194304u + 1048576u; }
  else if (seg == 6) { src = vw; doff = 4194304u + 2097152u; }
  else               { src = ow; doff = 4194304u + 3145728u; }
  const size_t i = ((size_t)blockIdx.x * 256 + threadIdx.x) * 4;
  float4v v = *(const float4v*)(src + i);
  short4v p;
#pragma unroll
  for (int r = 0; r < 4; ++r) p[r] = (short)f2bf(v[r]);
  *(short4v*)(dst + doff + i) = p;
}

// ---------------------------------------------------------------------------
// GEMM: out = X @ W^T + bias (unchanged from round 2).
// ---------------------------------------------------------------------------
__global__ __launch_bounds__(256, 2) void gemm_kernel(
    const unsigned short* __restrict__ X,
    const unsigned short* __restrict__ W0, const unsigned short* __restrict__ W1,
    const unsigned short* __restrict__ W2,
    const float* __restrict__ Bi0, const float* __restrict__ Bi1,
    const float* __restrict__ Bi2,
    unsigned short* O0, unsigned short* O1, unsigned short* O2,
    float* OutF, int md0, int md1, int md2)
{
  const int z = blockIdx.z;
  const unsigned short* W  = (z == 0) ? W0  : ((z == 1) ? W1  : W2);
  const float* Bi          = (z == 0) ? Bi0 : ((z == 1) ? Bi1 : Bi2);
  unsigned short* Out      = (z == 0) ? O0  : ((z == 1) ? O1  : O2);
  const int mode           = (z == 0) ? md0 : ((z == 1) ? md1 : md2);

  __shared__ __align__(16) char smem[128 * 32 * 2 * 2];
  char* As = smem;
  char* Bs = smem + 128 * 32 * 2;

  const int t = threadIdx.x, l = t & 63;
  const int w = t >> 6, lr = l & 15, lg = l >> 4;
  const int n0 = blockIdx.x * 128, m0 = blockIdx.y * 128;
  const int wm = (w >> 1) * 64, wn = (w & 1) * 64;

  float4v acc[4][4];
#pragma unroll
  for (int i = 0; i < 4; ++i)
#pragma unroll
    for (int j = 0; j < 4; ++j) acc[i][j] = (float4v){0.f, 0.f, 0.f, 0.f};

  const int c0 = t, c1 = t + 256;
  const int r0 = c0 >> 2, k80 = (c0 & 3) * 8;
  const int r1 = c1 >> 2, k81 = (c1 & 3) * 8;

  for (int k0 = 0; k0 < 1024; k0 += 32) {
    __syncthreads();
    gload_lds16(X + (size_t)(m0 + r0) * 1024 + k0 + k80, As + c0 * 16);
    gload_lds16(X + (size_t)(m0 + r1) * 1024 + k0 + k81, As + c1 * 16);
    gload_lds16(W + (size_t)(n0 + r0) * 1024 + k0 + k80, Bs + c0 * 16);
    gload_lds16(W + (size_t)(n0 + r1) * 1024 + k0 + k81, Bs + c1 * 16);
    __syncthreads();

    short8 af[4], bfr[4];
#pragma unroll
    for (int i = 0; i < 4; ++i)
      af[i] = *(const short8*)(As + (wm + i * 16 + lr) * 64 + lg * 16);
#pragma unroll
    for (int j = 0; j < 4; ++j)
      bfr[j] = *(const short8*)(Bs + (wn + j * 16 + lr) * 64 + lg * 16);
#pragma unroll
    for (int i = 0; i < 4; ++i)
#pragma unroll
      for (int j = 0; j < 4; ++j)
        acc[i][j] = __builtin_amdgcn_mfma_f32_16x16x32_bf16(af[i], bfr[j], acc[i][j], 0, 0, 0);
  }

  float bv[4];
#pragma unroll
  for (int j = 0; j < 4; ++j) bv[j] = Bi[n0 + wn + j * 16 + lr];

#pragma unroll
  for (int i = 0; i < 4; ++i) {
    const int rowb = m0 + wm + i * 16 + lg * 4;
#pragma unroll
    for (int j = 0; j < 4; ++j) {
      const int col = n0 + wn + j * 16 + lr;
      if (mode == 2) {
        const int b = rowb >> 11, s = rowb & 2047;
        const int hh = col >> 6, d = col & 63;
        short4v pk;
#pragma unroll
        for (int r = 0; r < 4; ++r) pk[r] = (short)f2bf(acc[i][j][r] + bv[j]);
        *(short4v*)(Out + ((size_t)(b * H_ + hh) * HD_ + d) * S_ + s) = pk;
      } else if (mode == 1) {
#pragma unroll
        for (int r = 0; r < 4; ++r) {
          const int row = rowb + r;
          const int b = row >> 11, s = row & 2047;
          const int hh = col >> 6, d = col & 63;
          Out[((size_t)(b * H_ + hh) * S_ + s) * HD_ + d] = f2bf(acc[i][j][r] + bv[j]);
        }
      } else {
#pragma unroll
        for (int r = 0; r < 4; ++r)
          OutF[(size_t)(rowb + r) * 1024 + col] = acc[i][j][r] + bv[j];
      }
    }
  }
}

// ---------------------------------------------------------------------------
// Flash attention, restructured:
//  - BLOCK_M=64 (4 waves x 16 rows), BLOCK_N=64
//  - each block processes Q-tile pair {ib, 31-ib}: exactly 33 iters/block,
//    512 blocks -> 2 blocks/CU, perfectly balanced, no tail
//  - async double-buffered K/V staging via global_load_lds (16B), XOR-swizzled
//    LDS layout (swizzle folded into the global source address)
//  - one barrier per iteration (P is wave-private: lgkm waits only)
//  - row-sum via MFMA with a ones B-fragment (kills the sum shuffle chain)
// ---------------------------------------------------------------------------
__global__ __launch_bounds__(256, 2) void attn_kernel(
    const unsigned short* __restrict__ Q, const unsigned short* __restrict__ K,
    const unsigned short* __restrict__ VT, unsigned short* __restrict__ O)
{
  // K dbuf 2x8KB + V dbuf 2x8KB + P 4x(16x144B)
  __shared__ __align__(16) char smem[32768 + 9216];

  const int t = threadIdx.x, l = t & 63;
  const int w = t >> 6, lr = l & 15, lg = l >> 4;
  const int ibp = blockIdx.x, bh = blockIdx.y;
  const int h = bh & 15;

  const unsigned short* qbp = Q + (size_t)bh * S_ * HD_;
  const unsigned short* kbp = K + (size_t)bh * S_ * HD_;
  const unsigned short* vbp = VT + (size_t)bh * HD_ * S_;

  const float slope2 = __builtin_amdgcn_exp2f(-0.5f * (float)(h + 1)) * LOG2E;
  const float qksc = 0.125f * LOG2E;

  char* pw = smem + 32768 + w * (16 * 144);  // wave-private P

  short8 ones;
#pragma unroll
  for (int e = 0; e < 8; ++e) ones[e] = (short)0x3F80;  // bf16 1.0

  // staging chunk mapping (XOR swizzle): chunk g holds row=g>>3, col-chunk (g&7)^(row&7)
  const int g0 = t, g1 = t + 256;
  const int sr0 = g0 >> 3, sc0 = (g0 & 7) ^ (sr0 & 7);
  const int sr1 = g1 >> 3, sc1 = (g1 & 7) ^ (sr1 & 7);

  // fragment read offsets (swizzled): row*128B with col-chunk ^ (row&7)
  const int fchunk = ((4 + lg) ^ (lr & 7)) * 16;   // ks=1 chunk byte offset
  const int fchunk0 = ((lg) ^ (lr & 7)) * 16;      // ks=0

  for (int tl = 0; tl < 2; ++tl) {
    const int it = tl ? (31 - ibp) : ibp;
    const int qrow = it * 64 + w * 16;

    short8 qf[2];
#pragma unroll
    for (int ks = 0; ks < 2; ++ks)
      qf[ks] = *(const short8*)(qbp + (size_t)(qrow + lr) * HD_ + ks * 32 + lg * 8);

    float4v o_acc[4];
#pragma unroll
    for (int dt = 0; dt < 4; ++dt) o_acc[dt] = (float4v){0.f, 0.f, 0.f, 0.f};
    float m_st[4], l_st[4];
#pragma unroll
    for (int r = 0; r < 4; ++r) { m_st[r] = -1e30f; l_st[r] = 0.f; }

    // prefetch j=0 into buffer 0
    gload_lds16(kbp + (size_t)sr0 * HD_ + sc0 * 8, smem + g0 * 16);
    gload_lds16(kbp + (size_t)sr1 * HD_ + sc1 * 8, smem + g1 * 16);
    gload_lds16(vbp + (size_t)sr0 * S_ + sc0 * 8, smem + 16384 + g0 * 16);
    gload_lds16(vbp + (size_t)sr1 * S_ + sc1 * 8, smem + 16384 + g1 * 16);
    __syncthreads();

    for (int j = 0; j <= it; ++j) {
      const int cur = j & 1;
      char* Ks = smem + (cur ? 8192 : 0);
      char* Vs = smem + 16384 + (cur ? 8192 : 0);
      if (j < it) {  // async prefetch next tile into the other buffer
        char* Kn = smem + (cur ? 0 : 8192);
        char* Vn = smem + 16384 + (cur ? 0 : 8192);
        const int jn = j + 1;
        gload_lds16(kbp + (size_t)(jn * 64 + sr0) * HD_ + sc0 * 8, Kn + g0 * 16);
        gload_lds16(kbp + (size_t)(jn * 64 + sr1) * HD_ + sc1 * 8, Kn + g1 * 16);
        gload_lds16(vbp + (size_t)sr0 * S_ + jn * 64 + sc0 * 8, Vn + g0 * 16);
        gload_lds16(vbp + (size_t)sr1 * S_ + jn * 64 + sc1 * 8, Vn + g1 * 16);
      }

      // S = Q K^T (16 rows x 64 keys)
      float4v s_acc[4];
#pragma unroll
      for (int nj = 0; nj < 4; ++nj) {
        s_acc[nj] = (float4v){0.f, 0.f, 0.f, 0.f};
        short8 kf0 = *(const short8*)(Ks + (nj * 16 + lr) * 128 + fchunk0);
        s_acc[nj] = __builtin_amdgcn_mfma_f32_16x16x32_bf16(qf[0], kf0, s_acc[nj], 0, 0, 0);
        short8 kf1 = *(const short8*)(Ks + (nj * 16 + lr) * 128 + fchunk);
        s_acc[nj] = __builtin_amdgcn_mfma_f32_16x16x32_bf16(qf[1], kf1, s_acc[nj], 0, 0, 0);
      }

      // scale + ALiBi column bias + causal mask (only the diagonal tile masks)
      const bool domask = (j == it);
#pragma unroll
      for (int nj = 0; nj < 4; ++nj) {
        const int kpos = j * 64 + nj * 16 + lr;
        const float cb = slope2 * (float)kpos;
#pragma unroll
        for (int r = 0; r < 4; ++r) {
          float sv = s_acc[nj][r] * qksc + cb;
          if (domask && kpos > qrow + lg * 4 + r) sv = -1e30f;
          s_acc[nj][r] = sv;
        }
      }

      // online softmax: max reduce (16-lane shuffle) + exp2; sum comes from MFMA
      float ar[4];
#pragma unroll
      for (int r = 0; r < 4; ++r) {
        float mx = fmaxf(fmaxf(s_acc[0][r], s_acc[1][r]),
                         fmaxf(s_acc[2][r], s_acc[3][r]));
#pragma unroll
        for (int d = 1; d < 16; d <<= 1) mx = fmaxf(mx, __shfl_xor(mx, d, 64));
        const float mn = fmaxf(m_st[r], mx);
        ar[r] = __builtin_amdgcn_exp2f(m_st[r] - mn);
        m_st[r] = mn;
#pragma unroll
        for (int nj = 0; nj < 4; ++nj)
          s_acc[nj][r] = __builtin_amdgcn_exp2f(s_acc[nj][r] - mn);
#pragma unroll
        for (int dt = 0; dt < 4; ++dt) o_acc[dt][r] *= ar[r];
      }

      // P (C-layout) -> wave-private LDS [16 q rows][64 keys], stride 144B
#pragma unroll
      for (int nj = 0; nj < 4; ++nj)
#pragma unroll
        for (int r = 0; r < 4; ++r)
          *(unsigned short*)(pw + (lg * 4 + r) * 144 + (nj * 16 + lr) * 2) =
              f2bf(s_acc[nj][r]);

      short8 pf[2];
#pragma unroll
      for (int ks = 0; ks < 2; ++ks)
        pf[ks] = *(const short8*)(pw + lr * 144 + ks * 64 + lg * 16);

      // row-sum via MFMA against ones: rs[r] = rowsum(P[lg*4+r][:])
      float4v rs = (float4v){0.f, 0.f, 0.f, 0.f};
      rs = __builtin_amdgcn_mfma_f32_16x16x32_bf16(pf[0], ones, rs, 0, 0, 0);
      rs = __builtin_amdgcn_mfma_f32_16x16x32_bf16(pf[1], ones, rs, 0, 0, 0);
#pragma unroll
      for (int r = 0; r < 4; ++r) l_st[r] = ar[r] * l_st[r] + rs[r];

      // O += P V
#pragma unroll
      for (int dt = 0; dt < 4; ++dt) {
        short8 vf0 = *(const short8*)(Vs + (dt * 16 + lr) * 128 + fchunk0);
        o_acc[dt] = __builtin_amdgcn_mfma_f32_16x16x32_bf16(pf[0], vf0, o_acc[dt], 0, 0, 0);
        short8 vf1 = *(const short8*)(Vs + (dt * 16 + lr) * 128 + fchunk);
        o_acc[dt] = __builtin_amdgcn_mfma_f32_16x16x32_bf16(pf[1], vf1, o_acc[dt], 0, 0, 0);
      }
      __syncthreads();  // drains prefetch (vmcnt) + guards buffer swap
    }

    // finalize tile: O /= l, write bf16 [B*S, H*hd]
    const int brow = (bh >> 4) * S_;
#pragma unroll
    for (int r = 0; r < 4; ++r) {
      const float inv = 1.0f / l_st[r];
      const int qp = qrow + lg * 4 + r;
#pragma unroll
      for (int dt = 0; dt < 4; ++dt)
        O[(size_t)(brow + qp) * 1024 + h * 64 + dt * 16 + lr] = f2bf(o_acc[dt][r] * inv);
    }
  }
}

extern "C" void kernel_launch(void* const* d_in, const int* in_sizes, int n_in,
                              void* d_out, int out_size, void* d_ws, size_t ws_size,
                              hipStream_t stream) {
  (void)in_sizes; (void)n_in; (void)out_size; (void)ws_size;
  const float* x  = (const float*)d_in[0];
  const float* qw = (const float*)d_in[1];
  const float* qb = (const float*)d_in[2];
  const float* kw = (const float*)d_in[3];
  const float* kb = (const float*)d_in[4];
  const float* vw = (const float*)d_in[5];
  const float* vb = (const float*)d_in[6];
  const float* ow = (const float*)d_in[7];
  const float* ob = (const float*)d_in[8];
  float* out = (float*)d_out;

  unsigned short* xb  = (unsigned short*)d_ws;              // [4096,1024] bf16
  unsigned short* qwb = xb  + (size_t)M_ * D_;
  unsigned short* kwb = qwb + (size_t)D_ * D_;
  unsigned short* vwb = kwb + (size_t)D_ * D_;
  unsigned short* owb = vwb + (size_t)D_ * D_;
  unsigned short* qws = owb + (size_t)D_ * D_;              // [B,H,S,hd]
  unsigned short* kws = qws + (size_t)M_ * D_;              // [B,H,S,hd]
  unsigned short* vws = kws + (size_t)M_ * D_;              // [B,H,hd,S]
  unsigned short* aws = vws + (size_t)M_ * D_;              // [B*S, H*hd]

  cvt_kernel<<<dim3(1024, 8), dim3(256), 0, stream>>>(x, qw, kw, vw, ow, xb);
  gemm_kernel<<<dim3(8, 32, 3), dim3(256), 0, stream>>>(
      xb, qwb, kwb, vwb, qb, kb, vb, qws, kws, vws, out, 1, 1, 2);
  attn_kernel<<<dim3(16, 32), dim3(256), 0, stream>>>(qws, kws, vws, aws);
  gemm_kernel<<<dim3(8, 32, 1), dim3(256), 0, stream>>>(
      aws, owb, owb, owb, ob, ob, ob, aws, aws, aws, out, 0, 0, 0);
}

// Round 7
// 200.208 us; speedup vs baseline: 1.4735x; 1.0269x over previous
//
#include <hip/hip_runtime.h>

typedef __attribute__((ext_vector_type(8))) short short8;
typedef __attribute__((ext_vector_type(4))) float float4v;
typedef __attribute__((ext_vector_type(4))) short short4v;

#define B_ 2
#define S_ 2048
#define D_ 1024
#define H_ 16
#define HD_ 64
#define M_ 4096
#define LOG2E 1.442695040888963f

__device__ __forceinline__ unsigned short f2bf(float f) {
  unsigned int u = __builtin_bit_cast(unsigned int, f);
  u += 0x7fffu + ((u >> 16) & 1u);   // RNE (finite values only)
  return (unsigned short)(u >> 16);
}

__device__ __forceinline__ void gload_lds16(const void* g, void* l) {
  __builtin_amdgcn_global_load_lds(
      (const __attribute__((address_space(1))) void*)g,
      (__attribute__((address_space(3))) void*)l, 16, 0, 0);
}

// ---------------------------------------------------------------------------
// f32 -> bf16 cast: x (4 segs of 1M) + qw/kw/vw/ow (1M each) into d_ws.
// ---------------------------------------------------------------------------
__global__ __launch_bounds__(256, 4) void cvt_kernel(
    const float* __restrict__ x,  const float* __restrict__ qw,
    const float* __restrict__ kw, const float* __restrict__ vw,
    const float* __restrict__ ow, unsigned short* __restrict__ dst)
{
  const int seg = blockIdx.y;
  const float* src;
  size_t doff;
  if (seg < 4)       { src = x + (size_t)seg * 1048576; doff = (size_t)seg * 1048576; }
  else if (seg == 4) { src = qw; doff = 4194304u; }
  else if (seg == 5) { src = kw; doff = 4194304u + 1048576u; }
  else if (seg == 6) { src = vw; doff = 4194304u + 2097152u; }
  else               { src = ow; doff = 4194304u + 3145728u; }
  const size_t i = ((size_t)blockIdx.x * 256 + threadIdx.x) * 4;
  float4v v = *(const float4v*)(src + i);
  short4v p;
#pragma unroll
  for (int r = 0; r < 4; ++r) p[r] = (short)f2bf(v[r]);
  *(short4v*)(dst + doff + i) = p;
}

// ---------------------------------------------------------------------------
// GEMM: out = X @ W^T + bias (round-3 exact, non-templated, 128x128 tile).
// mode 0: f32 [4096,1024]; mode 1: bf16 [B,H,S,hd]; mode 2: bf16 [B,H,hd,S].
// ---------------------------------------------------------------------------
__global__ __launch_bounds__(256, 2) void gemm_kernel(
    const unsigned short* __restrict__ X,
    const unsigned short* __restrict__ W0, const unsigned short* __restrict__ W1,
    const unsigned short* __restrict__ W2,
    const float* __restrict__ Bi0, const float* __restrict__ Bi1,
    const float* __restrict__ Bi2,
    unsigned short* O0, unsigned short* O1, unsigned short* O2,
    float* OutF, int md0, int md1, int md2)
{
  const int z = blockIdx.z;
  const unsigned short* W  = (z == 0) ? W0  : ((z == 1) ? W1  : W2);
  const float* Bi          = (z == 0) ? Bi0 : ((z == 1) ? Bi1 : Bi2);
  unsigned short* Out      = (z == 0) ? O0  : ((z == 1) ? O1  : O2);
  const int mode           = (z == 0) ? md0 : ((z == 1) ? md1 : md2);

  __shared__ __align__(16) char smem[128 * 32 * 2 * 2];
  char* As = smem;
  char* Bs = smem + 128 * 32 * 2;

  const int t = threadIdx.x, l = t & 63;
  const int w = t >> 6, lr = l & 15, lg = l >> 4;
  const int n0 = blockIdx.x * 128, m0 = blockIdx.y * 128;
  const int wm = (w >> 1) * 64, wn = (w & 1) * 64;

  float4v acc[4][4];
#pragma unroll
  for (int i = 0; i < 4; ++i)
#pragma unroll
    for (int j = 0; j < 4; ++j) acc[i][j] = (float4v){0.f, 0.f, 0.f, 0.f};

  const int c0 = t, c1 = t + 256;
  const int r0 = c0 >> 2, k80 = (c0 & 3) * 8;
  const int r1 = c1 >> 2, k81 = (c1 & 3) * 8;

  for (int k0 = 0; k0 < 1024; k0 += 32) {
    __syncthreads();
    gload_lds16(X + (size_t)(m0 + r0) * 1024 + k0 + k80, As + c0 * 16);
    gload_lds16(X + (size_t)(m0 + r1) * 1024 + k0 + k81, As + c1 * 16);
    gload_lds16(W + (size_t)(n0 + r0) * 1024 + k0 + k80, Bs + c0 * 16);
    gload_lds16(W + (size_t)(n0 + r1) * 1024 + k0 + k81, Bs + c1 * 16);
    __syncthreads();

    short8 af[4], bfr[4];
#pragma unroll
    for (int i = 0; i < 4; ++i)
      af[i] = *(const short8*)(As + (wm + i * 16 + lr) * 64 + lg * 16);
#pragma unroll
    for (int j = 0; j < 4; ++j)
      bfr[j] = *(const short8*)(Bs + (wn + j * 16 + lr) * 64 + lg * 16);
#pragma unroll
    for (int i = 0; i < 4; ++i)
#pragma unroll
      for (int j = 0; j < 4; ++j)
        acc[i][j] = __builtin_amdgcn_mfma_f32_16x16x32_bf16(af[i], bfr[j], acc[i][j], 0, 0, 0);
  }

  float bv[4];
#pragma unroll
  for (int j = 0; j < 4; ++j) bv[j] = Bi[n0 + wn + j * 16 + lr];

#pragma unroll
  for (int i = 0; i < 4; ++i) {
    const int rowb = m0 + wm + i * 16 + lg * 4;
#pragma unroll
    for (int j = 0; j < 4; ++j) {
      const int col = n0 + wn + j * 16 + lr;
      if (mode == 2) {
        const int b = rowb >> 11, s = rowb & 2047;
        const int hh = col >> 6, d = col & 63;
        short4v pk;
#pragma unroll
        for (int r = 0; r < 4; ++r) pk[r] = (short)f2bf(acc[i][j][r] + bv[j]);
        *(short4v*)(Out + ((size_t)(b * H_ + hh) * HD_ + d) * S_ + s) = pk;
      } else if (mode == 1) {
#pragma unroll
        for (int r = 0; r < 4; ++r) {
          const int row = rowb + r;
          const int b = row >> 11, s = row & 2047;
          const int hh = col >> 6, d = col & 63;
          Out[((size_t)(b * H_ + hh) * S_ + s) * HD_ + d] = f2bf(acc[i][j][r] + bv[j]);
        }
      } else {
#pragma unroll
        for (int r = 0; r < 4; ++r)
          OutF[(size_t)(rowb + r) * 1024 + col] = acc[i][j][r] + bv[j];
      }
    }
  }
}

// ---------------------------------------------------------------------------
// Flash attention (round-3 verified per-tile code; ONLY change: grid is
// 1024 single-tile blocks in LPT order instead of 512 paired blocks).
//  - grid (bh=32, y=32), it = 31 - y  -> heaviest tiles dispatched first
//  - 4 waves x 16 q-rows; async double-buffered K/V via global_load_lds,
//    XOR swizzle; one barrier/iter; wave-private P; RNE P-store;
//    rowsum via ones-MFMA
// ---------------------------------------------------------------------------
__global__ __launch_bounds__(256, 2) void attn_kernel(
    const unsigned short* __restrict__ Q, const unsigned short* __restrict__ K,
    const unsigned short* __restrict__ VT, unsigned short* __restrict__ O)
{
  // K dbuf 2x8KB + V dbuf 2x8KB + P 4x(16x144B)
  __shared__ __align__(16) char smem[32768 + 9216];

  const int t = threadIdx.x, l = t & 63;
  const int w = t >> 6, lr = l & 15, lg = l >> 4;
  const int bh = blockIdx.x;
  const int it = 31 - (int)blockIdx.y;   // LPT: heavy tiles first
  const int h = bh & 15;

  const unsigned short* qbp = Q + (size_t)bh * S_ * HD_;
  const unsigned short* kbp = K + (size_t)bh * S_ * HD_;
  const unsigned short* vbp = VT + (size_t)bh * HD_ * S_;

  const float slope2 = __builtin_amdgcn_exp2f(-0.5f * (float)(h + 1)) * LOG2E;
  const float qksc = 0.125f * LOG2E;

  char* pw = smem + 32768 + w * (16 * 144);  // wave-private P

  short8 ones;
#pragma unroll
  for (int e = 0; e < 8; ++e) ones[e] = (short)0x3F80;  // bf16 1.0

  // staging chunk mapping (XOR swizzle)
  const int g0 = t, g1 = t + 256;
  const int sr0 = g0 >> 3, sc0 = (g0 & 7) ^ (sr0 & 7);
  const int sr1 = g1 >> 3, sc1 = (g1 & 7) ^ (sr1 & 7);

  // fragment read offsets (swizzled)
  const int fchunk = ((4 + lg) ^ (lr & 7)) * 16;   // ks=1
  const int fchunk0 = ((lg) ^ (lr & 7)) * 16;      // ks=0

  const int qrow = it * 64 + w * 16;

  short8 qf[2];
#pragma unroll
  for (int ks = 0; ks < 2; ++ks)
    qf[ks] = *(const short8*)(qbp + (size_t)(qrow + lr) * HD_ + ks * 32 + lg * 8);

  float4v o_acc[4];
#pragma unroll
  for (int dt = 0; dt < 4; ++dt) o_acc[dt] = (float4v){0.f, 0.f, 0.f, 0.f};
  float m_st[4], l_st[4];
#pragma unroll
  for (int r = 0; r < 4; ++r) { m_st[r] = -1e30f; l_st[r] = 0.f; }

  // prefetch j=0 into buffer 0
  gload_lds16(kbp + (size_t)sr0 * HD_ + sc0 * 8, smem + g0 * 16);
  gload_lds16(kbp + (size_t)sr1 * HD_ + sc1 * 8, smem + g1 * 16);
  gload_lds16(vbp + (size_t)sr0 * S_ + sc0 * 8, smem + 16384 + g0 * 16);
  gload_lds16(vbp + (size_t)sr1 * S_ + sc1 * 8, smem + 16384 + g1 * 16);
  __syncthreads();

  for (int j = 0; j <= it; ++j) {
    const int cur = j & 1;
    char* Ks = smem + (cur ? 8192 : 0);
    char* Vs = smem + 16384 + (cur ? 8192 : 0);
    if (j < it) {  // async prefetch next tile into the other buffer
      char* Kn = smem + (cur ? 0 : 8192);
      char* Vn = smem + 16384 + (cur ? 0 : 8192);
      const int jn = j + 1;
      gload_lds16(kbp + (size_t)(jn * 64 + sr0) * HD_ + sc0 * 8, Kn + g0 * 16);
      gload_lds16(kbp + (size_t)(jn * 64 + sr1) * HD_ + sc1 * 8, Kn + g1 * 16);
      gload_lds16(vbp + (size_t)sr0 * S_ + jn * 64 + sc0 * 8, Vn + g0 * 16);
      gload_lds16(vbp + (size_t)sr1 * S_ + jn * 64 + sc1 * 8, Vn + g1 * 16);
    }

    // S = Q K^T (16 rows x 64 keys)
    float4v s_acc[4];
#pragma unroll
    for (int nj = 0; nj < 4; ++nj) {
      s_acc[nj] = (float4v){0.f, 0.f, 0.f, 0.f};
      short8 kf0 = *(const short8*)(Ks + (nj * 16 + lr) * 128 + fchunk0);
      s_acc[nj] = __builtin_amdgcn_mfma_f32_16x16x32_bf16(qf[0], kf0, s_acc[nj], 0, 0, 0);
      short8 kf1 = *(const short8*)(Ks + (nj * 16 + lr) * 128 + fchunk);
      s_acc[nj] = __builtin_amdgcn_mfma_f32_16x16x32_bf16(qf[1], kf1, s_acc[nj], 0, 0, 0);
    }

    // scale + ALiBi column bias + causal mask (diagonal tile only)
    const bool domask = (j == it);
#pragma unroll
    for (int nj = 0; nj < 4; ++nj) {
      const int kpos = j * 64 + nj * 16 + lr;
      const float cb = slope2 * (float)kpos;
#pragma unroll
      for (int r = 0; r < 4; ++r) {
        float sv = s_acc[nj][r] * qksc + cb;
        if (domask && kpos > qrow + lg * 4 + r) sv = -1e30f;
        s_acc[nj][r] = sv;
      }
    }

    // online softmax: max reduce (16-lane shuffle) + exp2; sum via rowsum-MFMA
    float ar[4];
#pragma unroll
    for (int r = 0; r < 4; ++r) {
      float mx = fmaxf(fmaxf(s_acc[0][r], s_acc[1][r]),
                       fmaxf(s_acc[2][r], s_acc[3][r]));
#pragma unroll
      for (int d = 1; d < 16; d <<= 1) mx = fmaxf(mx, __shfl_xor(mx, d, 64));
      const float mn = fmaxf(m_st[r], mx);
      ar[r] = __builtin_amdgcn_exp2f(m_st[r] - mn);
      m_st[r] = mn;
#pragma unroll
      for (int nj = 0; nj < 4; ++nj)
        s_acc[nj][r] = __builtin_amdgcn_exp2f(s_acc[nj][r] - mn);
#pragma unroll
      for (int dt = 0; dt < 4; ++dt) o_acc[dt][r] *= ar[r];
    }

    // P (C-layout) -> wave-private LDS [16 q rows][64 keys], stride 144B (RNE)
#pragma unroll
    for (int nj = 0; nj < 4; ++nj)
#pragma unroll
      for (int r = 0; r < 4; ++r)
        *(unsigned short*)(pw + (lg * 4 + r) * 144 + (nj * 16 + lr) * 2) =
            f2bf(s_acc[nj][r]);

    short8 pf[2];
#pragma unroll
    for (int ks = 0; ks < 2; ++ks)
      pf[ks] = *(const short8*)(pw + lr * 144 + ks * 64 + lg * 16);

    // row-sum via MFMA against ones
    float4v rs = (float4v){0.f, 0.f, 0.f, 0.f};
    rs = __builtin_amdgcn_mfma_f32_16x16x32_bf16(pf[0], ones, rs, 0, 0, 0);
    rs = __builtin_amdgcn_mfma_f32_16x16x32_bf16(pf[1], ones, rs, 0, 0, 0);
#pragma unroll
    for (int r = 0; r < 4; ++r) l_st[r] = ar[r] * l_st[r] + rs[r];

    // O += P V
#pragma unroll
    for (int dt = 0; dt < 4; ++dt) {
      short8 vf0 = *(const short8*)(Vs + (dt * 16 + lr) * 128 + fchunk0);
      o_acc[dt] = __builtin_amdgcn_mfma_f32_16x16x32_bf16(pf[0], vf0, o_acc[dt], 0, 0, 0);
      short8 vf1 = *(const short8*)(Vs + (dt * 16 + lr) * 128 + fchunk);
      o_acc[dt] = __builtin_amdgcn_mfma_f32_16x16x32_bf16(pf[1], vf1, o_acc[dt], 0, 0, 0);
    }
    __syncthreads();  // drains prefetch (vmcnt) + guards buffer swap
  }

  // finalize: O /= l, write bf16 [B*S, H*hd]
  const int brow = (bh >> 4) * S_;
#pragma unroll
  for (int r = 0; r < 4; ++r) {
    const float inv = 1.0f / l_st[r];
    const int qp = qrow + lg * 4 + r;
#pragma unroll
    for (int dt = 0; dt < 4; ++dt)
      O[(size_t)(brow + qp) * 1024 + h * 64 + dt * 16 + lr] = f2bf(o_acc[dt][r] * inv);
  }
}

extern "C" void kernel_launch(void* const* d_in, const int* in_sizes, int n_in,
                              void* d_out, int out_size, void* d_ws, size_t ws_size,
                              hipStream_t stream) {
  (void)in_sizes; (void)n_in; (void)out_size; (void)ws_size;
  const float* x  = (const float*)d_in[0];
  const float* qw = (const float*)d_in[1];
  const float* qb = (const float*)d_in[2];
  const float* kw = (const float*)d_in[3];
  const float* kb = (const float*)d_in[4];
  const float* vw = (const float*)d_in[5];
  const float* vb = (const float*)d_in[6];
  const float* ow = (const float*)d_in[7];
  const float* ob = (const float*)d_in[8];
  float* out = (float*)d_out;

  unsigned short* xb  = (unsigned short*)d_ws;              // [4096,1024] bf16
  unsigned short* qwb = xb  + (size_t)M_ * D_;
  unsigned short* kwb = qwb + (size_t)D_ * D_;
  unsigned short* vwb = kwb + (size_t)D_ * D_;
  unsigned short* owb = vwb + (size_t)D_ * D_;
  unsigned short* qws = owb + (size_t)D_ * D_;              // [B,H,S,hd]
  unsigned short* kws = qws + (size_t)M_ * D_;              // [B,H,S,hd]
  unsigned short* vws = kws + (size_t)M_ * D_;              // [B,H,hd,S]
  unsigned short* aws = vws + (size_t)M_ * D_;              // [B*S, H*hd]

  cvt_kernel<<<dim3(1024, 8), dim3(256), 0, stream>>>(x, qw, kw, vw, ow, xb);
  gemm_kernel<<<dim3(8, 32, 3), dim3(256), 0, stream>>>(
      xb, qwb, kwb, vwb, qb, kb, vb, qws, kws, vws, out, 1, 1, 2);
  attn_kernel<<<dim3(32, 32), dim3(256), 0, stream>>>(qws, kws, vws, aws);
  gemm_kernel<<<dim3(8, 32, 1), dim3(256), 0, stream>>>(
      aws, owb, owb, owb, ob, ob, ob, aws, aws, aws, out, 0, 0, 0);
}

// Round 9
// 193.342 us; speedup vs baseline: 1.5258x; 1.0355x over previous
//
#include <hip/hip_runtime.h>

typedef __attribute__((ext_vector_type(8))) short short8;
typedef __attribute__((ext_vector_type(4))) float float4v;
typedef __attribute__((ext_vector_type(4))) short short4v;

#define B_ 2
#define S_ 2048
#define D_ 1024
#define H_ 16
#define HD_ 64
#define M_ 4096
#define LOG2E 1.442695040888963f

__device__ __forceinline__ unsigned short f2bf(float f) {
  unsigned int u = __builtin_bit_cast(unsigned int, f);
  u += 0x7fffu + ((u >> 16) & 1u);   // RNE (finite values only)
  return (unsigned short)(u >> 16);
}

__device__ __forceinline__ void gload_lds16(const void* g, void* l) {
  __builtin_amdgcn_global_load_lds(
      (const __attribute__((address_space(1))) void*)g,
      (__attribute__((address_space(3))) void*)l, 16, 0, 0);
}

// ---------------------------------------------------------------------------
// f32 -> bf16 cast: x (4 segs of 1M) + qw/kw/vw/ow (1M each) into d_ws.
// (byte-identical to round 7)
// ---------------------------------------------------------------------------
__global__ __launch_bounds__(256, 4) void cvt_kernel(
    const float* __restrict__ x,  const float* __restrict__ qw,
    const float* __restrict__ kw, const float* __restrict__ vw,
    const float* __restrict__ ow, unsigned short* __restrict__ dst)
{
  const int seg = blockIdx.y;
  const float* src;
  size_t doff;
  if (seg < 4)       { src = x + (size_t)seg * 1048576; doff = (size_t)seg * 1048576; }
  else if (seg == 4) { src = qw; doff = 4194304u; }
  else if (seg == 5) { src = kw; doff = 4194304u + 1048576u; }
  else if (seg == 6) { src = vw; doff = 4194304u + 2097152u; }
  else               { src = ow; doff = 4194304u + 3145728u; }
  const size_t i = ((size_t)blockIdx.x * 256 + threadIdx.x) * 4;
  float4v v = *(const float4v*)(src + i);
  short4v p;
#pragma unroll
  for (int r = 0; r < 4; ++r) p[r] = (short)f2bf(v[r]);
  *(short4v*)(dst + doff + i) = p;
}

// ---------------------------------------------------------------------------
// GEMM: out = X @ W^T + bias (byte-identical to round 7; known good).
// ---------------------------------------------------------------------------
__global__ __launch_bounds__(256, 2) void gemm_kernel(
    const unsigned short* __restrict__ X,
    const unsigned short* __restrict__ W0, const unsigned short* __restrict__ W1,
    const unsigned short* __restrict__ W2,
    const float* __restrict__ Bi0, const float* __restrict__ Bi1,
    const float* __restrict__ Bi2,
    unsigned short* O0, unsigned short* O1, unsigned short* O2,
    float* OutF, int md0, int md1, int md2)
{
  const int z = blockIdx.z;
  const unsigned short* W  = (z == 0) ? W0  : ((z == 1) ? W1  : W2);
  const float* Bi          = (z == 0) ? Bi0 : ((z == 1) ? Bi1 : Bi2);
  unsigned short* Out      = (z == 0) ? O0  : ((z == 1) ? O1  : O2);
  const int mode           = (z == 0) ? md0 : ((z == 1) ? md1 : md2);

  __shared__ __align__(16) char smem[128 * 32 * 2 * 2];
  char* As = smem;
  char* Bs = smem + 128 * 32 * 2;

  const int t = threadIdx.x, l = t & 63;
  const int w = t >> 6, lr = l & 15, lg = l >> 4;
  const int n0 = blockIdx.x * 128, m0 = blockIdx.y * 128;
  const int wm = (w >> 1) * 64, wn = (w & 1) * 64;

  float4v acc[4][4];
#pragma unroll
  for (int i = 0; i < 4; ++i)
#pragma unroll
    for (int j = 0; j < 4; ++j) acc[i][j] = (float4v){0.f, 0.f, 0.f, 0.f};

  const int c0 = t, c1 = t + 256;
  const int r0 = c0 >> 2, k80 = (c0 & 3) * 8;
  const int r1 = c1 >> 2, k81 = (c1 & 3) * 8;

  for (int k0 = 0; k0 < 1024; k0 += 32) {
    __syncthreads();
    gload_lds16(X + (size_t)(m0 + r0) * 1024 + k0 + k80, As + c0 * 16);
    gload_lds16(X + (size_t)(m0 + r1) * 1024 + k0 + k81, As + c1 * 16);
    gload_lds16(W + (size_t)(n0 + r0) * 1024 + k0 + k80, Bs + c0 * 16);
    gload_lds16(W + (size_t)(n0 + r1) * 1024 + k0 + k81, Bs + c1 * 16);
    __syncthreads();

    short8 af[4], bfr[4];
#pragma unroll
    for (int i = 0; i < 4; ++i)
      af[i] = *(const short8*)(As + (wm + i * 16 + lr) * 64 + lg * 16);
#pragma unroll
    for (int j = 0; j < 4; ++j)
      bfr[j] = *(const short8*)(Bs + (wn + j * 16 + lr) * 64 + lg * 16);
#pragma unroll
    for (int i = 0; i < 4; ++i)
#pragma unroll
      for (int j = 0; j < 4; ++j)
        acc[i][j] = __builtin_amdgcn_mfma_f32_16x16x32_bf16(af[i], bfr[j], acc[i][j], 0, 0, 0);
  }

  float bv[4];
#pragma unroll
  for (int j = 0; j < 4; ++j) bv[j] = Bi[n0 + wn + j * 16 + lr];

#pragma unroll
  for (int i = 0; i < 4; ++i) {
    const int rowb = m0 + wm + i * 16 + lg * 4;
#pragma unroll
    for (int j = 0; j < 4; ++j) {
      const int col = n0 + wn + j * 16 + lr;
      if (mode == 2) {
        const int b = rowb >> 11, s = rowb & 2047;
        const int hh = col >> 6, d = col & 63;
        short4v pk;
#pragma unroll
        for (int r = 0; r < 4; ++r) pk[r] = (short)f2bf(acc[i][j][r] + bv[j]);
        *(short4v*)(Out + ((size_t)(b * H_ + hh) * HD_ + d) * S_ + s) = pk;
      } else if (mode == 1) {
#pragma unroll
        for (int r = 0; r < 4; ++r) {
          const int row = rowb + r;
          const int b = row >> 11, s = row & 2047;
          const int hh = col >> 6, d = col & 63;
          Out[((size_t)(b * H_ + hh) * S_ + s) * HD_ + d] = f2bf(acc[i][j][r] + bv[j]);
        }
      } else {
#pragma unroll
        for (int r = 0; r < 4; ++r)
          OutF[(size_t)(rowb + r) * 1024 + col] = acc[i][j][r] + bv[j];
      }
    }
  }
}

// ---------------------------------------------------------------------------
// Flash attention v4: S^T formulation, no P LDS round-trip.
//  - grid (bh=32, y=32), it = 31 - y (LPT); 4 waves x 16 q-rows
//  - K/V staging + double buffer + barrier: identical to round 7
//  - S^T = K.Q^T (operand-swapped MFMA; identical fragment loads)
//  - P^T stays in registers: C-layout == B-operand K=16 sublayout; two
//    16-key blocks packed into the K=32 fragment halves (same injection
//    on V^T side) -> PV uses the proven 16x16x32 intrinsic, zero cross-lane
//  - softmax: in-lane 16-max/sum + TWO shuffles; scalar m/l/alpha per lane
//  - O^T un-transposed once per block via wave-private LDS epilogue
// ---------------------------------------------------------------------------
__global__ __launch_bounds__(256, 2) void attn_kernel(
    const unsigned short* __restrict__ Q, const unsigned short* __restrict__ K,
    const unsigned short* __restrict__ VT, unsigned short* __restrict__ O)
{
  // K dbuf 2x8KB + V dbuf 2x8KB + per-wave transpose buf 4x4416B
  __shared__ __align__(16) char smem[32768 + 4 * 4416];

  const int t = threadIdx.x, l = t & 63;
  const int w = t >> 6, lr = l & 15, lg = l >> 4;
  const int bh = blockIdx.x;
  const int it = 31 - (int)blockIdx.y;   // LPT: heavy tiles first
  const int h = bh & 15;

  const unsigned short* qbp = Q + (size_t)bh * S_ * HD_;
  const unsigned short* kbp = K + (size_t)bh * S_ * HD_;
  const unsigned short* vbp = VT + (size_t)bh * HD_ * S_;

  const float slope2 = __builtin_amdgcn_exp2f(-0.5f * (float)(h + 1)) * LOG2E;
  const float qksc = 0.125f * LOG2E;

  char* tw = smem + 32768 + w * 4416;  // wave-private transpose buffer

  // staging chunk mapping (XOR swizzle) -- identical to round 7
  const int g0 = t, g1 = t + 256;
  const int sr0 = g0 >> 3, sc0 = (g0 & 7) ^ (sr0 & 7);
  const int sr1 = g1 >> 3, sc1 = (g1 & 7) ^ (sr1 & 7);

  // K fragment read offsets (swizzled) -- identical bytes to round 7
  const int fchunk = ((4 + lg) ^ (lr & 7)) * 16;   // ks=1
  const int fchunk0 = ((lg) ^ (lr & 7)) * 16;      // ks=0

  const int qrow = it * 64 + w * 16;
  const int qpos = qrow + lr;          // this lane's q (S^T col)

  // ALiBi per-element constants: slope2 * (nj*16 + lg*4 + r)
  float kb16[4][4];
#pragma unroll
  for (int nj = 0; nj < 4; ++nj)
#pragma unroll
    for (int r = 0; r < 4; ++r)
      kb16[nj][r] = slope2 * (float)(nj * 16 + lg * 4 + r);

  short8 qf[2];
#pragma unroll
  for (int ks = 0; ks < 2; ++ks)
    qf[ks] = *(const short8*)(qbp + (size_t)(qrow + lr) * HD_ + ks * 32 + lg * 8);

  float4v o_acc[4];   // O^T[d-block dt][q]: col=lane&15=q, row=quad*4+r=d
#pragma unroll
  for (int dt = 0; dt < 4; ++dt) o_acc[dt] = (float4v){0.f, 0.f, 0.f, 0.f};
  float m_st = -1e30f, l_st = 0.f;   // per-lane scalars (q = lane&15)

  // prefetch j=0 into buffer 0
  gload_lds16(kbp + (size_t)sr0 * HD_ + sc0 * 8, smem + g0 * 16);
  gload_lds16(kbp + (size_t)sr1 * HD_ + sc1 * 8, smem + g1 * 16);
  gload_lds16(vbp + (size_t)sr0 * S_ + sc0 * 8, smem + 16384 + g0 * 16);
  gload_lds16(vbp + (size_t)sr1 * S_ + sc1 * 8, smem + 16384 + g1 * 16);
  __syncthreads();

  for (int j = 0; j <= it; ++j) {
    const int cur = j & 1;
    char* Ks = smem + (cur ? 8192 : 0);
    char* Vs = smem + 16384 + (cur ? 8192 : 0);
    if (j < it) {  // async prefetch next tile into the other buffer
      char* Kn = smem + (cur ? 0 : 8192);
      char* Vn = smem + 16384 + (cur ? 0 : 8192);
      const int jn = j + 1;
      gload_lds16(kbp + (size_t)(jn * 64 + sr0) * HD_ + sc0 * 8, Kn + g0 * 16);
      gload_lds16(kbp + (size_t)(jn * 64 + sr1) * HD_ + sc1 * 8, Kn + g1 * 16);
      gload_lds16(vbp + (size_t)sr0 * S_ + jn * 64 + sc0 * 8, Vn + g0 * 16);
      gload_lds16(vbp + (size_t)sr1 * S_ + jn * 64 + sc1 * 8, Vn + g1 * 16);
    }

    // S^T = K Q^T: s_acc[nj][r] = S[key = j*64 + nj*16 + lg*4 + r][q = qpos]
    float4v s_acc[4];
#pragma unroll
    for (int nj = 0; nj < 4; ++nj) {
      s_acc[nj] = (float4v){0.f, 0.f, 0.f, 0.f};
      short8 kf0 = *(const short8*)(Ks + (nj * 16 + lr) * 128 + fchunk0);
      s_acc[nj] = __builtin_amdgcn_mfma_f32_16x16x32_bf16(kf0, qf[0], s_acc[nj], 0, 0, 0);
      short8 kf1 = *(const short8*)(Ks + (nj * 16 + lr) * 128 + fchunk);
      s_acc[nj] = __builtin_amdgcn_mfma_f32_16x16x32_bf16(kf1, qf[1], s_acc[nj], 0, 0, 0);
    }

    // scale + ALiBi column bias; causal mask on the diagonal tile only
    const float cj = slope2 * (float)(j * 64);
#pragma unroll
    for (int nj = 0; nj < 4; ++nj)
#pragma unroll
      for (int r = 0; r < 4; ++r)
        s_acc[nj][r] = s_acc[nj][r] * qksc + (cj + kb16[nj][r]);
    if (j == it) {
#pragma unroll
      for (int nj = 0; nj < 4; ++nj)
#pragma unroll
        for (int r = 0; r < 4; ++r) {
          const int kpos = j * 64 + nj * 16 + lg * 4 + r;
          if (kpos > qpos) s_acc[nj][r] = -1e30f;
        }
    }

    // online softmax: in-lane reduce over 16 + 2 cross-quad shuffles
    float mx = s_acc[0][0];
#pragma unroll
    for (int nj = 0; nj < 4; ++nj)
#pragma unroll
      for (int r = 0; r < 4; ++r) mx = fmaxf(mx, s_acc[nj][r]);
    mx = fmaxf(mx, __shfl_xor(mx, 16, 64));
    mx = fmaxf(mx, __shfl_xor(mx, 32, 64));
    const float mn = fmaxf(m_st, mx);
    const float alpha = __builtin_amdgcn_exp2f(m_st - mn);
    m_st = mn;
    float rsum = 0.f;
#pragma unroll
    for (int nj = 0; nj < 4; ++nj)
#pragma unroll
      for (int r = 0; r < 4; ++r) {
        const float p = __builtin_amdgcn_exp2f(s_acc[nj][r] - mn);
        s_acc[nj][r] = p;
        rsum += p;
      }
    rsum += __shfl_xor(rsum, 16, 64);
    rsum += __shfl_xor(rsum, 32, 64);
    l_st = alpha * l_st + rsum;
#pragma unroll
    for (int dt = 0; dt < 4; ++dt)
#pragma unroll
      for (int r = 0; r < 4; ++r) o_acc[dt][r] *= alpha;

    // P^T -> bf16 K=32 B-fragments: halves = two 16-key blocks (njp*2, njp*2+1)
    short8 pT[2];
#pragma unroll
    for (int njp = 0; njp < 2; ++njp)
#pragma unroll
      for (int jj = 0; jj < 4; ++jj) {
        pT[njp][jj]     = (short)f2bf(s_acc[njp * 2][jj]);
        pT[njp][jj + 4] = (short)f2bf(s_acc[njp * 2 + 1][jj]);
      }

    // O^T += V^T P^T  (A = V^T fragments with the same two-block K-injection)
    const int vcl = lr & 7;
#pragma unroll
    for (int dt = 0; dt < 4; ++dt) {
      const char* rowp = Vs + (dt * 16 + lr) * 128;
#pragma unroll
      for (int njp = 0; njp < 2; ++njp) {
        const int cA = ((njp * 4 + (lg >> 1)) ^ vcl) * 16 + (lg & 1) * 8;
        const int cB = ((njp * 4 + 2 + (lg >> 1)) ^ vcl) * 16 + (lg & 1) * 8;
        short4v v0 = *(const short4v*)(rowp + cA);
        short4v v1 = *(const short4v*)(rowp + cB);
        short8 vf8;
#pragma unroll
        for (int e = 0; e < 4; ++e) { vf8[e] = v0[e]; vf8[e + 4] = v1[e]; }
        o_acc[dt] = __builtin_amdgcn_mfma_f32_16x16x32_bf16(vf8, pT[njp], o_acc[dt], 0, 0, 0);
      }
    }
    __syncthreads();  // drains prefetch (vmcnt) + guards buffer swap
  }

  // epilogue: un-transpose O^T via wave-private LDS, coalesced bf16 store
  // layout: [64 d][17 f32] + 16 f32 l-values at offset 4352
#pragma unroll
  for (int dt = 0; dt < 4; ++dt)
#pragma unroll
    for (int r = 0; r < 4; ++r)
      *(float*)(tw + ((dt * 16 + lg * 4 + r) * 17 + lr) * 4) = o_acc[dt][r];
  if (lg == 0) *(float*)(tw + 4352 + lr * 4) = l_st;
  // (compiler inserts lgkm wait: same-pointer LDS dependence, r3/r7-proven)

  const int q2 = l >> 2, dbase = (l & 3) * 16;
  const float invl = 1.0f / *(const float*)(tw + 4352 + q2 * 4);
  short8 os[2];
#pragma unroll
  for (int i = 0; i < 16; ++i) {
    const float v = *(const float*)(tw + ((dbase + i) * 17 + q2) * 4) * invl;
    os[i >> 3][i & 7] = (short)f2bf(v);
  }
  const int brow = (bh >> 4) * S_;
  unsigned short* op = O + (size_t)(brow + qrow + q2) * 1024 + h * 64 + dbase;
  *(short8*)op = os[0];
  *(short8*)(op + 8) = os[1];
}

extern "C" void kernel_launch(void* const* d_in, const int* in_sizes, int n_in,
                              void* d_out, int out_size, void* d_ws, size_t ws_size,
                              hipStream_t stream) {
  (void)in_sizes; (void)n_in; (void)out_size; (void)ws_size;
  const float* x  = (const float*)d_in[0];
  const float* qw = (const float*)d_in[1];
  const float* qb = (const float*)d_in[2];
  const float* kw = (const float*)d_in[3];
  const float* kb = (const float*)d_in[4];
  const float* vw = (const float*)d_in[5];
  const float* vb = (const float*)d_in[6];
  const float* ow = (const float*)d_in[7];
  const float* ob = (const float*)d_in[8];
  float* out = (float*)d_out;

  unsigned short* xb  = (unsigned short*)d_ws;              // [4096,1024] bf16
  unsigned short* qwb = xb  + (size_t)M_ * D_;
  unsigned short* kwb = qwb + (size_t)D_ * D_;
  unsigned short* vwb = kwb + (size_t)D_ * D_;
  unsigned short* owb = vwb + (size_t)D_ * D_;
  unsigned short* qws = owb + (size_t)D_ * D_;              // [B,H,S,hd]
  unsigned short* kws = qws + (size_t)M_ * D_;              // [B,H,S,hd]
  unsigned short* vws = kws + (size_t)M_ * D_;              // [B,H,hd,S]
  unsigned short* aws = vws + (size_t)M_ * D_;              // [B*S, H*hd]

  cvt_kernel<<<dim3(1024, 8), dim3(256), 0, stream>>>(x, qw, kw, vw, ow, xb);
  gemm_kernel<<<dim3(8, 32, 3), dim3(256), 0, stream>>>(
      xb, qwb, kwb, vwb, qb, kb, vb, qws, kws, vws, out, 1, 1, 2);
  attn_kernel<<<dim3(32, 32), dim3(256), 0, stream>>>(qws, kws, vws, aws);
  gemm_kernel<<<dim3(8, 32, 1), dim3(256), 0, stream>>>(
      aws, owb, owb, owb, ob, ob, ob, aws, aws, aws, out, 0, 0, 0);
}